// Round 15
// baseline (431.111 us; speedup 1.0000x reference)
//
#include <hip/hip_runtime.h>
#include <hip/hip_fp16.h>
#include <math.h>

#define SCALING_F 0.46211715726000974f   // tanh(0.5)
#define MAXNORM_F 0.996f                 // 1 - BALL_EPS
#define MINNORM_F 1e-15f
#define BN_EPS_F  1e-5f

typedef _Float16 v8h __attribute__((ext_vector_type(8)));
typedef float    v4f __attribute__((ext_vector_type(4)));

// reduce over the 16-lane group holding one row
__device__ __forceinline__ float rsum16(float v) {
  v += __shfl_xor(v, 1, 64);
  v += __shfl_xor(v, 2, 64);
  v += __shfl_xor(v, 4, 64);
  v += __shfl_xor(v, 8, 64);
  return v;
}

__device__ __forceinline__ void rsum16x6(float& a, float& b, float& c,
                                         float& d, float& e, float& f) {
#pragma unroll
  for (int o = 1; o <= 8; o <<= 1) {
    a += __shfl_xor(a, o, 64);
    b += __shfl_xor(b, o, 64);
    c += __shfl_xor(c, o, 64);
    d += __shfl_xor(d, o, 64);
    e += __shfl_xor(e, o, 64);
    f += __shfl_xor(f, o, 64);
  }
}

__device__ __forceinline__ float h2f(float v) {   // fp16 round-trip
  return __half2float(__float2half(v));
}

// accumulate 8 halfs (as uint4) into float[8]
__device__ __forceinline__ void acc8(float* a, uint4 u) {
  __half2 h0 = *(__half2*)&u.x;
  __half2 h1 = *(__half2*)&u.y;
  __half2 h2 = *(__half2*)&u.z;
  __half2 h3 = *(__half2*)&u.w;
  a[0] += __low2float(h0); a[1] += __high2float(h0);
  a[2] += __low2float(h1); a[3] += __high2float(h1);
  a[4] += __low2float(h2); a[5] += __high2float(h2);
  a[6] += __low2float(h3); a[7] += __high2float(h3);
}

// load 4 halfs (8B) -> float[4]
__device__ __forceinline__ void load4f(const __half* p, float* a) {
  uint2 u = *(const uint2*)p;
  __half2 h0 = *(__half2*)&u.x;
  __half2 h1 = *(__half2*)&u.y;
  a[0] = __low2float(h0); a[1] = __high2float(h0);
  a[2] = __low2float(h1); a[3] = __high2float(h1);
}

// ---------------------------------------------------------------------------
// One-time weight conversion: fp32 row-major [K][64] -> fp16 transposed [n][k]
// ---------------------------------------------------------------------------
__global__ __launch_bounds__(256) void k_wcvt(
    const float* __restrict__ W0, const float* __restrict__ cW1,
    const float* __restrict__ cW2, int L,
    __half* __restrict__ W0T, __half* __restrict__ W1T, __half* __restrict__ W2T)
{
  int id = blockIdx.x * 256 + threadIdx.x;
  if (id < 64 * 128) {            // W0T[n][k], k<128
    int n = id >> 7, k = id & 127;
    W0T[id] = __float2half(W0[(size_t)k * 64 + n]);
  }
  if (id < L * 64 * 64) {         // W1T/W2T[l][n][k]
    int l = id >> 12, rem = id & 4095;
    int n = rem >> 6, k = rem & 63;
    W1T[id] = __float2half(cW1[(size_t)l * 4096 + k * 64 + n]);
    W2T[id] = __float2half(cW2[(size_t)l * 4096 + k * 64 + n]);
  }
}

// ---------------------------------------------------------------------------
// Graph boundaries from sorted batch: gstart[g] = first row with batch >= g.
// ---------------------------------------------------------------------------
__global__ __launch_bounds__(256) void k_gb(const int* __restrict__ batch,
                                            int N, int G, int* __restrict__ gstart)
{
  int r = blockIdx.x * 256 + threadIdx.x;
  if (r >= N) return;
  int b = batch[r];
  int prev = (r == 0) ? -1 : batch[r - 1];
  for (int g = prev + 1; g <= b; ++g) gstart[g] = r;
  if (r == N - 1)
    for (int g = b + 1; g <= G; ++g) gstart[g] = N;
}

// ---------------------------------------------------------------------------
// mm0 (64-row tile, MFMA, no LDS): X0 = relu(x_in @ W0 + b0) (K=128, fp16)
// ---------------------------------------------------------------------------
__global__ __launch_bounds__(256) void k_mm0(
    const float* __restrict__ A, const __half* __restrict__ BT,
    const float* __restrict__ bias, __half* __restrict__ X, int M)
{
  const int tid  = threadIdx.x;
  const int w    = tid >> 6;
  const int lane = tid & 63;
  const int q    = lane >> 4;
  const int i    = lane & 15;
  const int rblk = blockIdx.x * 64;
  const int arow = rblk + w * 16 + i;     // A-operand row for this lane

  v4f acc[4];
#pragma unroll
  for (int t = 0; t < 4; ++t) acc[t] = (v4f){0.f, 0.f, 0.f, 0.f};

#pragma unroll
  for (int hh = 0; hh < 4; ++hh) {
    v8h af = (v8h){0, 0, 0, 0, 0, 0, 0, 0};
    if (arow < M) {
      const float* p = &A[(size_t)arow * 128 + hh * 32 + q * 8];
      float4 fa = *(const float4*)p;
      float4 fb = *(const float4*)(p + 4);
      af[0] = (_Float16)fa.x; af[1] = (_Float16)fa.y;
      af[2] = (_Float16)fa.z; af[3] = (_Float16)fa.w;
      af[4] = (_Float16)fb.x; af[5] = (_Float16)fb.y;
      af[6] = (_Float16)fb.z; af[7] = (_Float16)fb.w;
    }
#pragma unroll
    for (int t = 0; t < 4; ++t) {
      v8h bf = *(const v8h*)&BT[(size_t)(t * 16 + i) * 128 + hh * 32 + q * 8];
      acc[t] = __builtin_amdgcn_mfma_f32_16x16x32_f16(af, bf, acc[t], 0, 0, 0);
    }
  }

#pragma unroll
  for (int j = 0; j < 4; ++j) {
    int row = rblk + w * 16 + 4 * q + j;
    if (row >= M) continue;
#pragma unroll
    for (int t = 0; t < 4; ++t)
      X[(size_t)row * 64 + i + 16 * t] =
          __float2half(fmaxf(acc[t][j] + bias[i + 16 * t], 0.f));
  }
}

// ---------------------------------------------------------------------------
// K1 (64-row tile, MFMA): h = relu((x[r] + sum_nb x[nb]) @ W1 + b1).
// Gather: 8 neighbors per wave-load, two rows interleaved, counted fast path
// (compiler can pipeline csr-index loads ahead of the row gathers).
// ---------------------------------------------------------------------------
__global__ __launch_bounds__(256, 6) void k_layer1(
    const __half* __restrict__ x, const int* __restrict__ rowptr,
    const unsigned short* __restrict__ csr, const __half* __restrict__ BT,
    const float* __restrict__ bias, __half* __restrict__ h,
    float* __restrict__ gstat, int M)
{
  __shared__ __half AsH[64][80];   // 160B rows (16B aligned)
  __shared__ float st[2048];
  const int tid  = threadIdx.x;
  const int w    = tid >> 6;
  const int lane = tid & 63;
  const int q    = lane >> 4;
  const int i    = lane & 15;
  const int g8   = lane >> 3;      // neighbor slot 0..7
  const int i8   = lane & 7;       // col group: cols 8*i8 .. +8
  const int rblk = blockIdx.x * 64;

  for (int pr = 0; pr < 8; ++pr) {
    int lr0 = w * 16 + 2 * pr;
    int lr1 = lr0 + 1;
    int r0 = rblk + lr0, r1 = rblk + lr1;
    bool v0 = (r0 < M), v1 = (r1 < M);
    float a0[8] = {0.f,0.f,0.f,0.f,0.f,0.f,0.f,0.f};
    float a1[8] = {0.f,0.f,0.f,0.f,0.f,0.f,0.f,0.f};
    int c0 = 0, e0 = 0, c1 = 0, e1 = 0;
    if (v0) { c0 = rowptr[r0]; e0 = rowptr[r0 + 1]; }
    if (v1) { c1 = rowptr[r1]; e1 = rowptr[r1 + 1]; }
    if (v0 && g8 == 0) acc8(a0, *(const uint4*)&x[(size_t)r0 * 64 + 8 * i8]);
    if (v1 && g8 == 0) acc8(a1, *(const uint4*)&x[(size_t)r1 * 64 + 8 * i8]);

    // counted fast path: both streams, 16 edges each per iteration
    int n16 = (e0 - c0) >> 4;
    int m16 = (e1 - c1) >> 4;
    int cnt = (n16 < m16) ? n16 : m16;
    for (int it = 0; it < cnt; ++it) {
      int n0a = csr[c0 + g8];
      int n0b = csr[c0 + 8 + g8];
      int n1a = csr[c1 + g8];
      int n1b = csr[c1 + 8 + g8];
      uint4 u0a = *(const uint4*)&x[(size_t)n0a * 64 + 8 * i8];
      uint4 u0b = *(const uint4*)&x[(size_t)n0b * 64 + 8 * i8];
      uint4 u1a = *(const uint4*)&x[(size_t)n1a * 64 + 8 * i8];
      uint4 u1b = *(const uint4*)&x[(size_t)n1b * 64 + 8 * i8];
      acc8(a0, u0a);
      acc8(a0, u0b);
      acc8(a1, u1a);
      acc8(a1, u1b);
      c0 += 16;
      c1 += 16;
    }
    while (c0 + 8 <= e0 || c1 + 8 <= e1) {
      bool d0 = (c0 + 8 <= e0);
      bool d1 = (c1 + 8 <= e1);
      int n0 = 0, n1 = 0;
      if (d0) n0 = csr[c0 + g8];
      if (d1) n1 = csr[c1 + g8];
      uint4 u0, u1;
      if (d0) u0 = *(const uint4*)&x[(size_t)n0 * 64 + 8 * i8];
      if (d1) u1 = *(const uint4*)&x[(size_t)n1 * 64 + 8 * i8];
      if (d0) { acc8(a0, u0); c0 += 8; }
      if (d1) { acc8(a1, u1); c1 += 8; }
    }
    {
      int rem0 = e0 - c0;
      int rem1 = e1 - c1;
      int n0 = 0, n1 = 0;
      if (g8 < rem0) n0 = csr[c0 + g8];
      if (g8 < rem1) n1 = csr[c1 + g8];
      uint4 u0, u1;
      if (g8 < rem0) u0 = *(const uint4*)&x[(size_t)n0 * 64 + 8 * i8];
      if (g8 < rem1) u1 = *(const uint4*)&x[(size_t)n1 * 64 + 8 * i8];
      if (g8 < rem0) acc8(a0, u0);
      if (g8 < rem1) acc8(a1, u1);
    }
#pragma unroll
    for (int k = 0; k < 8; ++k) {
      a0[k] += __shfl_xor(a0[k], 8, 64);
      a1[k] += __shfl_xor(a1[k], 8, 64);
      a0[k] += __shfl_xor(a0[k], 16, 64);
      a1[k] += __shfl_xor(a1[k], 16, 64);
      a0[k] += __shfl_xor(a0[k], 32, 64);
      a1[k] += __shfl_xor(a1[k], 32, 64);
    }
    if (g8 == 0) {
      __half hv0[8], hv1[8];
#pragma unroll
      for (int k = 0; k < 8; ++k) { hv0[k] = __float2half(a0[k]); hv1[k] = __float2half(a1[k]); }
      *(uint4*)&AsH[lr0][8 * i8] = *(uint4*)hv0;
      *(uint4*)&AsH[lr1][8 * i8] = *(uint4*)hv1;
    }
  }
  __syncthreads();

  v4f acc[4];
#pragma unroll
  for (int t = 0; t < 4; ++t) acc[t] = (v4f){0.f, 0.f, 0.f, 0.f};
#pragma unroll
  for (int hh = 0; hh < 2; ++hh) {
    v8h af = *(const v8h*)&AsH[w * 16 + i][hh * 32 + q * 8];
#pragma unroll
    for (int t = 0; t < 4; ++t) {
      v8h bf = *(const v8h*)&BT[(size_t)(t * 16 + i) * 64 + hh * 32 + q * 8];
      acc[t] = __builtin_amdgcn_mfma_f32_16x16x32_f16(af, bf, acc[t], 0, 0, 0);
    }
  }

  float s[4] = {0.f, 0.f, 0.f, 0.f}, qq[4] = {0.f, 0.f, 0.f, 0.f};
#pragma unroll
  for (int j = 0; j < 4; ++j) {
    int row = rblk + w * 16 + 4 * q + j;
    if (row >= M) continue;
#pragma unroll
    for (int t = 0; t < 4; ++t) {
      float v = h2f(fmaxf(acc[t][j] + bias[i + 16 * t], 0.f));
      h[(size_t)row * 64 + i + 16 * t] = __float2half(v);
      s[t] += v;
      qq[t] += v * v;
    }
  }
  {
    int g = w * 4 + q;
#pragma unroll
    for (int t = 0; t < 4; ++t) {
      st[g * 64 + i + 16 * t]        = s[t];
      st[1024 + g * 64 + i + 16 * t] = qq[t];
    }
    __syncthreads();
    if (tid < 64) {
      float a = 0.f, b = 0.f;
#pragma unroll
      for (int g2 = 0; g2 < 16; ++g2) {
        a += st[g2 * 64 + tid];
        b += st[1024 + g2 * 64 + tid];
      }
      atomicAdd(&gstat[tid], a);
      atomicAdd(&gstat[64 + tid], b);
    }
  }
}

// ---------------------------------------------------------------------------
// K2 (64-row tile, MFMA, no LDS): Xout = relu(BN(h) @ W2 + b2), col63 = 0.
// ---------------------------------------------------------------------------
__global__ __launch_bounds__(256) void k_layer2(
    const __half* __restrict__ A, const __half* __restrict__ BT,
    const float* __restrict__ bias,
    const float* __restrict__ gstat, const float* __restrict__ gamma,
    const float* __restrict__ beta,
    __half* __restrict__ Xout, int M)
{
  __shared__ float scl_s[64], shf_s[64];
  const int tid  = threadIdx.x;
  const int w    = tid >> 6;
  const int lane = tid & 63;
  const int q    = lane >> 4;
  const int i    = lane & 15;
  const int rblk = blockIdx.x * 64;
  const int arow = rblk + w * 16 + i;

  if (tid < 64) {
    float mu  = gstat[tid] / (float)M;
    float var = gstat[64 + tid] / (float)M - mu * mu;
    float sv  = gamma[tid] / sqrtf(var + BN_EPS_F);
    scl_s[tid] = sv;
    shf_s[tid] = beta[tid] - mu * sv;
  }
  __syncthreads();

  v4f acc[4];
#pragma unroll
  for (int t = 0; t < 4; ++t) acc[t] = (v4f){0.f, 0.f, 0.f, 0.f};
#pragma unroll
  for (int hh = 0; hh < 2; ++hh) {
    const int k0 = hh * 32 + q * 8;
    v8h af = (v8h){0, 0, 0, 0, 0, 0, 0, 0};
    {
      float hv[8] = {0,0,0,0,0,0,0,0};
      if (arow < M) {
        uint4 u = *(const uint4*)&A[(size_t)arow * 64 + k0];
        __half2 h0 = *(__half2*)&u.x;
        __half2 h1 = *(__half2*)&u.y;
        __half2 h2 = *(__half2*)&u.z;
        __half2 h3 = *(__half2*)&u.w;
        hv[0] = __low2float(h0); hv[1] = __high2float(h0);
        hv[2] = __low2float(h1); hv[3] = __high2float(h1);
        hv[4] = __low2float(h2); hv[5] = __high2float(h2);
        hv[6] = __low2float(h3); hv[7] = __high2float(h3);
      }
#pragma unroll
      for (int k = 0; k < 8; ++k)
        af[k] = (_Float16)fmaf(hv[k], scl_s[k0 + k], shf_s[k0 + k]);
    }
#pragma unroll
    for (int t = 0; t < 4; ++t) {
      v8h bf = *(const v8h*)&BT[(size_t)(t * 16 + i) * 64 + k0];
      acc[t] = __builtin_amdgcn_mfma_f32_16x16x32_f16(af, bf, acc[t], 0, 0, 0);
    }
  }

#pragma unroll
  for (int j = 0; j < 4; ++j) {
    int row = rblk + w * 16 + 4 * q + j;
    if (row >= M) continue;
#pragma unroll
    for (int t = 0; t < 4; ++t) {
      float v = fmaxf(acc[t][j] + bias[i + 16 * t], 0.f);
      if (i == 15 && t == 3) v = 0.f;   // col 63
      Xout[(size_t)row * 64 + i + 16 * t] = __float2half(v);
    }
  }
}

// ---------------------------------------------------------------------------
// zchain: per row, full hyperbolic recurrence in registers; xh -> Xh (fp32).
// ---------------------------------------------------------------------------
__global__ __launch_bounds__(256) void k_zchain(
    const __half* __restrict__ X0, const __half* __restrict__ X1,
    const __half* __restrict__ X2, const __half* __restrict__ X3,
    float* __restrict__ Xh, int M)
{
  const int tid = threadIdx.x;
  const int i   = tid & 15;
  const int row = blockIdx.x * 16 + (tid >> 4);
  const bool valid = (row < M);

  float x0[4] = {0,0,0,0}, x1[4] = {0,0,0,0}, x2[4] = {0,0,0,0}, x3[4] = {0,0,0,0};
  if (valid) {
    load4f(&X0[(size_t)row * 64 + 4 * i], x0);
    load4f(&X1[(size_t)row * 64 + 4 * i], x1);
    load4f(&X2[(size_t)row * 64 + 4 * i], x2);
    load4f(&X3[(size_t)row * 64 + 4 * i], x3);
  }

  float zc[4], zp[4] = {0.f, 0.f, 0.f, 0.f};
  {
    float sx = rsum16(x0[0]*x0[0] + x0[1]*x0[1] + x0[2]*x0[2] + x0[3]*x0[3]);
    float norm = fmaxf(sqrtf(sx), MINNORM_F);
    float s = ((norm > MAXNORM_F) ? (MAXNORM_F / norm) : 1.0f) * SCALING_F;
#pragma unroll
    for (int e = 0; e < 4; ++e) zc[e] = x0[e] * s;
  }

  const float* Xi[3] = {x1, x2, x3};
#pragma unroll
  for (int li = 0; li < 3; ++li) {
    const float* xv = Xi[li];

    float p1 = xv[0]*xv[0] + xv[1]*xv[1] + xv[2]*xv[2] + xv[3]*xv[3];
    float p2 = zc[0]*zc[0]+zc[1]*zc[1]+zc[2]*zc[2]+zc[3]*zc[3];
    float p3 = zp[0]*zp[0]+zp[1]*zp[1]+zp[2]*zp[2]+zp[3]*zp[3];
    float p4 = zp[0]*zc[0]+zp[1]*zc[1]+zp[2]*zc[2]+zp[3]*zc[3];
    float p5 = zp[0]*xv[0]+zp[1]*xv[1]+zp[2]*xv[2]+zp[3]*xv[3];
    float p6 = zc[0]*xv[0]+zc[1]*xv[1]+zc[2]*xv[2]+zc[3]*xv[3];
    rsum16x6(p1, p2, p3, p4, p5, p6);
    float zc63 = __shfl(zc[3], 15, 16);   // col 63 = lane 15, elem 3
    float zp63 = __shfl(zp[3], 15, 16);

    float nzc2 = fmaxf(p2, MINNORM_F);
    float icz  = 1.0f / nzc2;
    float na2  = p2 * icz * icz;
    float r2   = na2 - 1.0f;
    float a63  = zc63 * icz;

    float sxn = fmaxf(sqrtf(p1), MINNORM_F);
    float sc  = ((sxn > MAXNORM_F) ? (MAXNORM_F / sxn) : 1.0f) * SCALING_F;
    float Sch2   = sc * sc * p1;         // Σch² (ch63 = 0: col63 zeroed in X)
    float Szp_a  = p4 * icz;
    float Sa_ch  = sc * p6 * icz;
    float Szp_ch = sc * p5;
    float Su_a   = Szp_a - na2;
    float Su2    = p3 - 2.0f * Szp_a + na2;
    float nu2    = fmaxf(Su2, MINNORM_F);
    float t1     = r2 / nu2;
    float Szp22  = fmaxf(t1*t1*Su2 + 2.0f*t1*Su_a + na2, 0.0f);
    float npn    = fmaxf(sqrtf(Szp22), MINNORM_F);
    float ipn    = 1.0f / npn;
    float zp2_63 = t1 * (zp63 - a63) + a63;
    float Szp2ch = t1 * (Szp_ch - Sa_ch) + Sa_ch;
    float rdc    = -ipn * Szp2ch;
    float rdr    = 1.0f - 2.0f*ipn*zp2_63 + ipn*ipn*Szp22;
    float m2     = 2.0f * rdc / rdr;
    float Szp2a  = t1 * Su_a + na2;
    float Srr_a  = a63 - ipn * Szp2a;
    float Sc2a   = Sa_ch - m2 * Srr_a;
    float Sc22   = Sch2 - 2.0f*m2*rdc + m2*m2*rdr;
    float Sc2ma  = Sc22 - 2.0f*Sc2a + na2;
    float nu22   = fmaxf(Sc2ma, MINNORM_F);
    float t2     = r2 / nu22;

    float zn[4];
#pragma unroll
    for (int e = 0; e < 4; ++e) {
      float ai  = zc[e] * icz;
      float zp2 = t1 * (zp[e] - ai) + ai;
      float rri = ((i == 15 && e == 3) ? 1.0f : 0.0f) - ipn * zp2;
      float c2  = sc * xv[e] - m2 * rri;
      zn[e]     = t2 * (c2 - ai) + ai;
    }
#pragma unroll
    for (int e = 0; e < 4; ++e) { zp[e] = zc[e]; zc[e] = zn[e]; }
  }

  {
    float sz = rsum16(zc[0]*zc[0] + zc[1]*zc[1] + zc[2]*zc[2] + zc[3]*zc[3]);
    float yn  = fmaxf(sqrtf(sz), MINNORM_F);
    float t   = fminf(yn, 1.0f);
    float ath = 0.5f * logf((1.0f + t) / (1.0f - t));
    float wsc = ath / yn;
    if (valid) {
      float4 v = make_float4(zc[0] * wsc, zc[1] * wsc, zc[2] * wsc, zc[3] * wsc);
      *(float4*)&Xh[(size_t)row * 64 + 4 * i] = v;
    }
  }
}

// ---------------------------------------------------------------------------
// CSR build (csr entries are ushort: N < 65536)
// ---------------------------------------------------------------------------
__global__ __launch_bounds__(256) void k_deg(const int* __restrict__ dst, int E, int* deg) {
  int i0 = (blockIdx.x * 256 + threadIdx.x) * 4;
  if (i0 + 4 <= E) {
    int4 d = *(const int4*)&dst[i0];
    atomicAdd(&deg[d.x], 1);
    atomicAdd(&deg[d.y], 1);
    atomicAdd(&deg[d.z], 1);
    atomicAdd(&deg[d.w], 1);
  } else {
    for (int i = i0; i < E; ++i) atomicAdd(&deg[dst[i]], 1);
  }
}

__global__ __launch_bounds__(256) void k_scan1(const int* __restrict__ deg, int N,
                                               int* rowptr, int* bsum) {
  __shared__ int s[256];
  int t = threadIdx.x;
  int i = blockIdx.x * 256 + t;
  int v = (i < N) ? deg[i] : 0;
  s[t] = v;
  __syncthreads();
  for (int d = 1; d < 256; d <<= 1) {
    int add = (t >= d) ? s[t - d] : 0;
    __syncthreads();
    s[t] += add;
    __syncthreads();
  }
  if (i < N) rowptr[i] = s[t] - v;
  if (t == 255) bsum[blockIdx.x] = s[255];
}

__global__ __launch_bounds__(256) void k_scan2(const int* __restrict__ bsum, int NB, int* boff) {
  __shared__ int s[256];
  int t = threadIdx.x;
  int v = (t < NB) ? bsum[t] : 0;
  s[t] = v;
  __syncthreads();
  for (int d = 1; d < 256; d <<= 1) {
    int add = (t >= d) ? s[t - d] : 0;
    __syncthreads();
    s[t] += add;
    __syncthreads();
  }
  boff[t] = s[t] - v;
}

__global__ __launch_bounds__(256) void k_scan3(int* rowptr, const int* __restrict__ boff,
                                               int* cursor, int N, int E) {
  int i = blockIdx.x * 256 + threadIdx.x;
  if (i < N) {
    int v = rowptr[i] + boff[blockIdx.x];
    rowptr[i] = v;
    cursor[i] = v;
  }
  if (i == 0) rowptr[N] = E;
}

__global__ __launch_bounds__(256) void k_fill(const int* __restrict__ src,
                                              const int* __restrict__ dst, int E,
                                              int* cursor, unsigned short* __restrict__ csr) {
  int i0 = (blockIdx.x * 256 + threadIdx.x) * 4;
  if (i0 + 4 <= E) {
    int4 d = *(const int4*)&dst[i0];
    int4 s = *(const int4*)&src[i0];
    int p0 = atomicAdd(&cursor[d.x], 1);
    int p1 = atomicAdd(&cursor[d.y], 1);
    int p2 = atomicAdd(&cursor[d.z], 1);
    int p3 = atomicAdd(&cursor[d.w], 1);
    __builtin_nontemporal_store((unsigned short)s.x, &csr[p0]);
    __builtin_nontemporal_store((unsigned short)s.y, &csr[p1]);
    __builtin_nontemporal_store((unsigned short)s.z, &csr[p2]);
    __builtin_nontemporal_store((unsigned short)s.w, &csr[p3]);
  } else {
    for (int i = i0; i < E; ++i) {
      int p = atomicAdd(&cursor[dst[i]], 1);
      csr[p] = (unsigned short)src[i];
    }
  }
}

// ---------------------------------------------------------------------------
// Per-graph pooling (from Xh, rows gstart[g]..gstart[g+1]) + MLP + log_softmax
// ---------------------------------------------------------------------------
__global__ __launch_bounds__(128) void k_mlp(const float* __restrict__ Xh,
                                             const int* __restrict__ gstart,
                                             const float* __restrict__ fc1W, const float* __restrict__ fc1b,
                                             const float* __restrict__ fc2W, const float* __restrict__ fc2b,
                                             const float* __restrict__ fc3W, const float* __restrict__ fc3b,
                                             float* __restrict__ out) {
  __shared__ float p2s[2][64];
  __shared__ float p[64], o1[128], o2[64], lg[10], red[2];
  int g = blockIdx.x, t = threadIdx.x;
  int beg = gstart[g], end = gstart[g + 1];
  {
    int half = t >> 6, c = t & 63;
    float a = 0.f;
    int r = beg + half;
    for (; r + 6 <= end; r += 8) {         // 4 independent loads per iter
      float v0 = Xh[(size_t)(r + 0) * 64 + c];
      float v1 = Xh[(size_t)(r + 2) * 64 + c];
      float v2 = Xh[(size_t)(r + 4) * 64 + c];
      float v3 = Xh[(size_t)(r + 6) * 64 + c];
      a += (v0 + v1) + (v2 + v3);
    }
    for (; r < end; r += 2) a += Xh[(size_t)r * 64 + c];
    p2s[half][c] = a;
  }
  __syncthreads();
  if (t < 64) p[t] = p2s[0][t] + p2s[1][t];
  __syncthreads();
  {
    float a = fc1b[t];
    for (int k = 0; k < 64; ++k) a = fmaf(p[k], fc1W[k * 128 + t], a);
    o1[t] = fmaxf(a, 0.f);
  }
  __syncthreads();
  if (t < 64) {
    float a = fc2b[t];
    for (int k = 0; k < 128; ++k) a = fmaf(o1[k], fc2W[k * 64 + t], a);
    o2[t] = fmaxf(a, 0.f);
  }
  __syncthreads();
  if (t < 10) {
    float a = fc3b[t];
    for (int k = 0; k < 64; ++k) a = fmaf(o2[k], fc3W[k * 10 + t], a);
    lg[t] = a;
  }
  __syncthreads();
  if (t == 0) {
    float mx = lg[0];
    for (int j = 1; j < 10; ++j) mx = fmaxf(mx, lg[j]);
    float s = 0.f;
    for (int j = 0; j < 10; ++j) s += expf(lg[j] - mx);
    red[0] = mx;
    red[1] = logf(s);
  }
  __syncthreads();
  if (t < 10) out[(size_t)g * 10 + t] = lg[t] - red[0] - red[1];
}

// ---------------------------------------------------------------------------
extern "C" void kernel_launch(void* const* d_in, const int* in_sizes, int n_in,
                              void* d_out, int out_size, void* d_ws, size_t ws_size,
                              hipStream_t stream) {
  const float* x_in  = (const float*)d_in[0];
  const int*   ei    = (const int*)d_in[1];
  const int*   batch = (const int*)d_in[2];
  const float* W0    = (const float*)d_in[3];
  const float* b0    = (const float*)d_in[4];
  const float* cW1   = (const float*)d_in[5];
  const float* cb1   = (const float*)d_in[6];
  const float* gamma = (const float*)d_in[7];
  const float* beta  = (const float*)d_in[8];
  const float* cW2   = (const float*)d_in[9];
  const float* cb2   = (const float*)d_in[10];
  const float* fc1W  = (const float*)d_in[11];
  const float* fc1b  = (const float*)d_in[12];
  const float* fc2W  = (const float*)d_in[13];
  const float* fc2b  = (const float*)d_in[14];
  const float* fc3W  = (const float*)d_in[15];
  const float* fc3b  = (const float*)d_in[16];
  float* out = (float*)d_out;

  const int N = in_sizes[0] / 128;
  const int E = in_sizes[1] / 2;
  const int L = in_sizes[5] / (64 * 64);
  const int G = out_size / 10;
  const int* src = ei;
  const int* dst = ei + E;

  char* ws = (char*)d_ws;
  size_t off = 0;
  auto alloc = [&](size_t bytes) -> char* {
    char* p = ws + off;
    off += (bytes + 255) & ~(size_t)255;
    return p;
  };
  __half* X0  = (__half*)alloc((size_t)N * 64 * 2);
  __half* X1  = (__half*)alloc((size_t)N * 64 * 2);
  __half* X2  = (__half*)alloc((size_t)N * 64 * 2);
  __half* X3  = (__half*)alloc((size_t)N * 64 * 2);
  __half* Bf  = (__half*)alloc((size_t)N * 64 * 2);
  float*  Xh  = (float*)alloc((size_t)N * 64 * 4);
  __half* W0T = (__half*)alloc((size_t)64 * 128 * 2);
  __half* W1T = (__half*)alloc((size_t)L * 64 * 64 * 2);
  __half* W2T = (__half*)alloc((size_t)L * 64 * 64 * 2);
  int*    gstart = (int*)alloc((size_t)(G + 1) * 4);
  // ---- zeroed region: deg, gstatAll (contiguous) ----
  int*   deg  = (int*)alloc((size_t)N * 4);
  float* gstatAll = (float*)alloc((size_t)3 * 128 * 4);
  char*  zero_end = ws + off;
  // ---------------------------------------------------
  int*   rowptr = (int*)alloc((size_t)(N + 1) * 4);
  int*   cursor = (int*)alloc((size_t)N * 4);
  unsigned short* csr = (unsigned short*)alloc((size_t)E * 2);
  int*   bsum   = (int*)alloc(256 * 4);
  int*   boff   = (int*)alloc(256 * 4);
  __half* Xs[4] = {X0, X1, X2, X3};

  hipMemsetAsync(deg, 0, (size_t)(zero_end - (char*)deg), stream);

  const int mmGrid    = (N + 63) / 64;
  const int zcGrid    = (N + 15) / 16;
  const int edge4Grid = (E / 4 + 255) / 256 + 1;
  const int wcvtGrid  = (((L * 4096 > 8192) ? L * 4096 : 8192) + 255) / 256;

  k_wcvt<<<wcvtGrid, 256, 0, stream>>>(W0, cW1, cW2, L, W0T, W1T, W2T);
  k_gb<<<(N + 255) / 256, 256, 0, stream>>>(batch, N, G, gstart);

  k_mm0<<<mmGrid, 256, 0, stream>>>(x_in, W0T, b0, X0, N);

  k_deg<<<edge4Grid, 256, 0, stream>>>(dst, E, deg);
  const int NB = (N + 255) / 256;
  k_scan1<<<NB, 256, 0, stream>>>(deg, N, rowptr, bsum);
  k_scan2<<<1, 256, 0, stream>>>(bsum, NB, boff);
  k_scan3<<<NB, 256, 0, stream>>>(rowptr, boff, cursor, N, E);
  k_fill<<<edge4Grid, 256, 0, stream>>>(src, dst, E, cursor, csr);

  for (int i = 0; i < L; ++i) {
    float* gstat = gstatAll + (size_t)i * 128;
    k_layer1<<<mmGrid, 256, 0, stream>>>(Xs[i], rowptr, csr,
                                         W1T + (size_t)i * 4096, cb1 + i * 64,
                                         Bf, gstat, N);
    k_layer2<<<mmGrid, 256, 0, stream>>>(Bf, W2T + (size_t)i * 4096, cb2 + i * 64,
                                         gstat, gamma + i * 64, beta + i * 64,
                                         Xs[i + 1], N);
  }

  k_zchain<<<zcGrid, 256, 0, stream>>>(X0, X1, X2, X3, Xh, N);

  k_mlp<<<G, 128, 0, stream>>>(Xh, gstart, fc1W, fc1b, fc2W, fc2b, fc3W, fc3b, out);
}

// Round 16
// 411.305 us; speedup vs baseline: 1.0482x; 1.0482x over previous
//
#include <hip/hip_runtime.h>
#include <hip/hip_fp16.h>
#include <math.h>

#define SCALING_F 0.46211715726000974f   // tanh(0.5)
#define MAXNORM_F 0.996f                 // 1 - BALL_EPS
#define MINNORM_F 1e-15f
#define BN_EPS_F  1e-5f

typedef _Float16 v8h __attribute__((ext_vector_type(8)));
typedef float    v4f __attribute__((ext_vector_type(4)));

// reduce over the 16-lane group holding one row
__device__ __forceinline__ float rsum16(float v) {
  v += __shfl_xor(v, 1, 64);
  v += __shfl_xor(v, 2, 64);
  v += __shfl_xor(v, 4, 64);
  v += __shfl_xor(v, 8, 64);
  return v;
}

__device__ __forceinline__ void rsum16x6(float& a, float& b, float& c,
                                         float& d, float& e, float& f) {
#pragma unroll
  for (int o = 1; o <= 8; o <<= 1) {
    a += __shfl_xor(a, o, 64);
    b += __shfl_xor(b, o, 64);
    c += __shfl_xor(c, o, 64);
    d += __shfl_xor(d, o, 64);
    e += __shfl_xor(e, o, 64);
    f += __shfl_xor(f, o, 64);
  }
}

__device__ __forceinline__ float h2f(float v) {   // fp16 round-trip
  return __half2float(__float2half(v));
}

// accumulate 8 halfs (as uint4) into float[8]
__device__ __forceinline__ void acc8(float* a, uint4 u) {
  __half2 h0 = *(__half2*)&u.x;
  __half2 h1 = *(__half2*)&u.y;
  __half2 h2 = *(__half2*)&u.z;
  __half2 h3 = *(__half2*)&u.w;
  a[0] += __low2float(h0); a[1] += __high2float(h0);
  a[2] += __low2float(h1); a[3] += __high2float(h1);
  a[4] += __low2float(h2); a[5] += __high2float(h2);
  a[6] += __low2float(h3); a[7] += __high2float(h3);
}

// load 4 halfs (8B) -> float[4]
__device__ __forceinline__ void load4f(const __half* p, float* a) {
  uint2 u = *(const uint2*)p;
  __half2 h0 = *(__half2*)&u.x;
  __half2 h1 = *(__half2*)&u.y;
  a[0] = __low2float(h0); a[1] = __high2float(h0);
  a[2] = __low2float(h1); a[3] = __high2float(h1);
}

// ---------------------------------------------------------------------------
// One-time weight conversion: fp32 row-major [K][64] -> fp16 transposed [n][k]
// ---------------------------------------------------------------------------
__global__ __launch_bounds__(256) void k_wcvt(
    const float* __restrict__ W0, const float* __restrict__ cW1,
    const float* __restrict__ cW2, int L,
    __half* __restrict__ W0T, __half* __restrict__ W1T, __half* __restrict__ W2T)
{
  int id = blockIdx.x * 256 + threadIdx.x;
  if (id < 64 * 128) {            // W0T[n][k], k<128
    int n = id >> 7, k = id & 127;
    W0T[id] = __float2half(W0[(size_t)k * 64 + n]);
  }
  if (id < L * 64 * 64) {         // W1T/W2T[l][n][k]
    int l = id >> 12, rem = id & 4095;
    int n = rem >> 6, k = rem & 63;
    W1T[id] = __float2half(cW1[(size_t)l * 4096 + k * 64 + n]);
    W2T[id] = __float2half(cW2[(size_t)l * 4096 + k * 64 + n]);
  }
}

// ---------------------------------------------------------------------------
// Graph boundaries from sorted batch: gstart[g] = first row with batch >= g.
// ---------------------------------------------------------------------------
__global__ __launch_bounds__(256) void k_gb(const int* __restrict__ batch,
                                            int N, int G, int* __restrict__ gstart)
{
  int r = blockIdx.x * 256 + threadIdx.x;
  if (r >= N) return;
  int b = batch[r];
  int prev = (r == 0) ? -1 : batch[r - 1];
  for (int g = prev + 1; g <= b; ++g) gstart[g] = r;
  if (r == N - 1)
    for (int g = b + 1; g <= G; ++g) gstart[g] = N;
}

// ---------------------------------------------------------------------------
// mm0 (64-row tile, MFMA, no LDS): X0 = relu(x_in @ W0 + b0) (K=128, fp16)
// ---------------------------------------------------------------------------
__global__ __launch_bounds__(256) void k_mm0(
    const float* __restrict__ A, const __half* __restrict__ BT,
    const float* __restrict__ bias, __half* __restrict__ X, int M)
{
  const int tid  = threadIdx.x;
  const int w    = tid >> 6;
  const int lane = tid & 63;
  const int q    = lane >> 4;
  const int i    = lane & 15;
  const int rblk = blockIdx.x * 64;
  const int arow = rblk + w * 16 + i;     // A-operand row for this lane

  v4f acc[4];
#pragma unroll
  for (int t = 0; t < 4; ++t) acc[t] = (v4f){0.f, 0.f, 0.f, 0.f};

#pragma unroll
  for (int hh = 0; hh < 4; ++hh) {
    v8h af = (v8h){0, 0, 0, 0, 0, 0, 0, 0};
    if (arow < M) {
      const float* p = &A[(size_t)arow * 128 + hh * 32 + q * 8];
      float4 fa = *(const float4*)p;
      float4 fb = *(const float4*)(p + 4);
      af[0] = (_Float16)fa.x; af[1] = (_Float16)fa.y;
      af[2] = (_Float16)fa.z; af[3] = (_Float16)fa.w;
      af[4] = (_Float16)fb.x; af[5] = (_Float16)fb.y;
      af[6] = (_Float16)fb.z; af[7] = (_Float16)fb.w;
    }
#pragma unroll
    for (int t = 0; t < 4; ++t) {
      v8h bf = *(const v8h*)&BT[(size_t)(t * 16 + i) * 128 + hh * 32 + q * 8];
      acc[t] = __builtin_amdgcn_mfma_f32_16x16x32_f16(af, bf, acc[t], 0, 0, 0);
    }
  }

#pragma unroll
  for (int j = 0; j < 4; ++j) {
    int row = rblk + w * 16 + 4 * q + j;
    if (row >= M) continue;
#pragma unroll
    for (int t = 0; t < 4; ++t)
      X[(size_t)row * 64 + i + 16 * t] =
          __float2half(fmaxf(acc[t][j] + bias[i + 16 * t], 0.f));
  }
}

// ---------------------------------------------------------------------------
// K1 (64-row tile, MFMA): h = relu((x[r] + sum_nb x[nb]) @ W1 + b1).
// Gather: 8 neighbors per wave-load, two rows interleaved, counted fast path.
// ---------------------------------------------------------------------------
__global__ __launch_bounds__(256, 6) void k_layer1(
    const __half* __restrict__ x, const int* __restrict__ rowptr,
    const unsigned short* __restrict__ csr, const __half* __restrict__ BT,
    const float* __restrict__ bias, __half* __restrict__ h,
    float* __restrict__ gstat, int M)
{
  __shared__ __half AsH[64][80];   // 160B rows (16B aligned)
  __shared__ float st[2048];
  const int tid  = threadIdx.x;
  const int w    = tid >> 6;
  const int lane = tid & 63;
  const int q    = lane >> 4;
  const int i    = lane & 15;
  const int g8   = lane >> 3;      // neighbor slot 0..7
  const int i8   = lane & 7;       // col group: cols 8*i8 .. +8
  const int rblk = blockIdx.x * 64;

  for (int pr = 0; pr < 8; ++pr) {
    int lr0 = w * 16 + 2 * pr;
    int lr1 = lr0 + 1;
    int r0 = rblk + lr0, r1 = rblk + lr1;
    bool v0 = (r0 < M), v1 = (r1 < M);
    float a0[8] = {0.f,0.f,0.f,0.f,0.f,0.f,0.f,0.f};
    float a1[8] = {0.f,0.f,0.f,0.f,0.f,0.f,0.f,0.f};
    int c0 = 0, e0 = 0, c1 = 0, e1 = 0;
    if (v0) { c0 = rowptr[r0]; e0 = rowptr[r0 + 1]; }
    if (v1) { c1 = rowptr[r1]; e1 = rowptr[r1 + 1]; }
    if (v0 && g8 == 0) acc8(a0, *(const uint4*)&x[(size_t)r0 * 64 + 8 * i8]);
    if (v1 && g8 == 0) acc8(a1, *(const uint4*)&x[(size_t)r1 * 64 + 8 * i8]);

    // counted fast path: both streams, 16 edges each per iteration
    int n16 = (e0 - c0) >> 4;
    int m16 = (e1 - c1) >> 4;
    int cnt = (n16 < m16) ? n16 : m16;
    for (int it = 0; it < cnt; ++it) {
      int n0a = csr[c0 + g8];
      int n0b = csr[c0 + 8 + g8];
      int n1a = csr[c1 + g8];
      int n1b = csr[c1 + 8 + g8];
      uint4 u0a = *(const uint4*)&x[(size_t)n0a * 64 + 8 * i8];
      uint4 u0b = *(const uint4*)&x[(size_t)n0b * 64 + 8 * i8];
      uint4 u1a = *(const uint4*)&x[(size_t)n1a * 64 + 8 * i8];
      uint4 u1b = *(const uint4*)&x[(size_t)n1b * 64 + 8 * i8];
      acc8(a0, u0a);
      acc8(a0, u0b);
      acc8(a1, u1a);
      acc8(a1, u1b);
      c0 += 16;
      c1 += 16;
    }
    while (c0 + 8 <= e0 || c1 + 8 <= e1) {
      bool d0 = (c0 + 8 <= e0);
      bool d1 = (c1 + 8 <= e1);
      int n0 = 0, n1 = 0;
      if (d0) n0 = csr[c0 + g8];
      if (d1) n1 = csr[c1 + g8];
      uint4 u0, u1;
      if (d0) u0 = *(const uint4*)&x[(size_t)n0 * 64 + 8 * i8];
      if (d1) u1 = *(const uint4*)&x[(size_t)n1 * 64 + 8 * i8];
      if (d0) { acc8(a0, u0); c0 += 8; }
      if (d1) { acc8(a1, u1); c1 += 8; }
    }
    {
      int rem0 = e0 - c0;
      int rem1 = e1 - c1;
      int n0 = 0, n1 = 0;
      if (g8 < rem0) n0 = csr[c0 + g8];
      if (g8 < rem1) n1 = csr[c1 + g8];
      uint4 u0, u1;
      if (g8 < rem0) u0 = *(const uint4*)&x[(size_t)n0 * 64 + 8 * i8];
      if (g8 < rem1) u1 = *(const uint4*)&x[(size_t)n1 * 64 + 8 * i8];
      if (g8 < rem0) acc8(a0, u0);
      if (g8 < rem1) acc8(a1, u1);
    }
#pragma unroll
    for (int k = 0; k < 8; ++k) {
      a0[k] += __shfl_xor(a0[k], 8, 64);
      a1[k] += __shfl_xor(a1[k], 8, 64);
      a0[k] += __shfl_xor(a0[k], 16, 64);
      a1[k] += __shfl_xor(a1[k], 16, 64);
      a0[k] += __shfl_xor(a0[k], 32, 64);
      a1[k] += __shfl_xor(a1[k], 32, 64);
    }
    if (g8 == 0) {
      __half hv0[8], hv1[8];
#pragma unroll
      for (int k = 0; k < 8; ++k) { hv0[k] = __float2half(a0[k]); hv1[k] = __float2half(a1[k]); }
      *(uint4*)&AsH[lr0][8 * i8] = *(uint4*)hv0;
      *(uint4*)&AsH[lr1][8 * i8] = *(uint4*)hv1;
    }
  }
  __syncthreads();

  v4f acc[4];
#pragma unroll
  for (int t = 0; t < 4; ++t) acc[t] = (v4f){0.f, 0.f, 0.f, 0.f};
#pragma unroll
  for (int hh = 0; hh < 2; ++hh) {
    v8h af = *(const v8h*)&AsH[w * 16 + i][hh * 32 + q * 8];
#pragma unroll
    for (int t = 0; t < 4; ++t) {
      v8h bf = *(const v8h*)&BT[(size_t)(t * 16 + i) * 64 + hh * 32 + q * 8];
      acc[t] = __builtin_amdgcn_mfma_f32_16x16x32_f16(af, bf, acc[t], 0, 0, 0);
    }
  }

  float s[4] = {0.f, 0.f, 0.f, 0.f}, qq[4] = {0.f, 0.f, 0.f, 0.f};
#pragma unroll
  for (int j = 0; j < 4; ++j) {
    int row = rblk + w * 16 + 4 * q + j;
    if (row >= M) continue;
#pragma unroll
    for (int t = 0; t < 4; ++t) {
      float v = h2f(fmaxf(acc[t][j] + bias[i + 16 * t], 0.f));
      h[(size_t)row * 64 + i + 16 * t] = __float2half(v);
      s[t] += v;
      qq[t] += v * v;
    }
  }
  {
    int g = w * 4 + q;
#pragma unroll
    for (int t = 0; t < 4; ++t) {
      st[g * 64 + i + 16 * t]        = s[t];
      st[1024 + g * 64 + i + 16 * t] = qq[t];
    }
    __syncthreads();
    if (tid < 64) {
      float a = 0.f, b = 0.f;
#pragma unroll
      for (int g2 = 0; g2 < 16; ++g2) {
        a += st[g2 * 64 + tid];
        b += st[1024 + g2 * 64 + tid];
      }
      atomicAdd(&gstat[tid], a);
      atomicAdd(&gstat[64 + tid], b);
    }
  }
}

// ---------------------------------------------------------------------------
// K2 (64-row tile, MFMA, no LDS): Xout = relu(BN(h) @ W2 + b2), col63 = 0.
// ---------------------------------------------------------------------------
__global__ __launch_bounds__(256) void k_layer2(
    const __half* __restrict__ A, const __half* __restrict__ BT,
    const float* __restrict__ bias,
    const float* __restrict__ gstat, const float* __restrict__ gamma,
    const float* __restrict__ beta,
    __half* __restrict__ Xout, int M)
{
  __shared__ float scl_s[64], shf_s[64];
  const int tid  = threadIdx.x;
  const int w    = tid >> 6;
  const int lane = tid & 63;
  const int q    = lane >> 4;
  const int i    = lane & 15;
  const int rblk = blockIdx.x * 64;
  const int arow = rblk + w * 16 + i;

  if (tid < 64) {
    float mu  = gstat[tid] / (float)M;
    float var = gstat[64 + tid] / (float)M - mu * mu;
    float sv  = gamma[tid] / sqrtf(var + BN_EPS_F);
    scl_s[tid] = sv;
    shf_s[tid] = beta[tid] - mu * sv;
  }
  __syncthreads();

  v4f acc[4];
#pragma unroll
  for (int t = 0; t < 4; ++t) acc[t] = (v4f){0.f, 0.f, 0.f, 0.f};
#pragma unroll
  for (int hh = 0; hh < 2; ++hh) {
    const int k0 = hh * 32 + q * 8;
    v8h af = (v8h){0, 0, 0, 0, 0, 0, 0, 0};
    {
      float hv[8] = {0,0,0,0,0,0,0,0};
      if (arow < M) {
        uint4 u = *(const uint4*)&A[(size_t)arow * 64 + k0];
        __half2 h0 = *(__half2*)&u.x;
        __half2 h1 = *(__half2*)&u.y;
        __half2 h2 = *(__half2*)&u.z;
        __half2 h3 = *(__half2*)&u.w;
        hv[0] = __low2float(h0); hv[1] = __high2float(h0);
        hv[2] = __low2float(h1); hv[3] = __high2float(h1);
        hv[4] = __low2float(h2); hv[5] = __high2float(h2);
        hv[6] = __low2float(h3); hv[7] = __high2float(h3);
      }
#pragma unroll
      for (int k = 0; k < 8; ++k)
        af[k] = (_Float16)fmaf(hv[k], scl_s[k0 + k], shf_s[k0 + k]);
    }
#pragma unroll
    for (int t = 0; t < 4; ++t) {
      v8h bf = *(const v8h*)&BT[(size_t)(t * 16 + i) * 64 + k0];
      acc[t] = __builtin_amdgcn_mfma_f32_16x16x32_f16(af, bf, acc[t], 0, 0, 0);
    }
  }

#pragma unroll
  for (int j = 0; j < 4; ++j) {
    int row = rblk + w * 16 + 4 * q + j;
    if (row >= M) continue;
#pragma unroll
    for (int t = 0; t < 4; ++t) {
      float v = fmaxf(acc[t][j] + bias[i + 16 * t], 0.f);
      if (i == 15 && t == 3) v = 0.f;   // col 63
      Xout[(size_t)row * 64 + i + 16 * t] = __float2half(v);
    }
  }
}

// ---------------------------------------------------------------------------
// zchain: per row, full hyperbolic recurrence in registers; xh -> Xh (fp16).
// ---------------------------------------------------------------------------
__global__ __launch_bounds__(256) void k_zchain(
    const __half* __restrict__ X0, const __half* __restrict__ X1,
    const __half* __restrict__ X2, const __half* __restrict__ X3,
    __half* __restrict__ Xh, int M)
{
  const int tid = threadIdx.x;
  const int i   = tid & 15;
  const int row = blockIdx.x * 16 + (tid >> 4);
  const bool valid = (row < M);

  float x0[4] = {0,0,0,0}, x1[4] = {0,0,0,0}, x2[4] = {0,0,0,0}, x3[4] = {0,0,0,0};
  if (valid) {
    load4f(&X0[(size_t)row * 64 + 4 * i], x0);
    load4f(&X1[(size_t)row * 64 + 4 * i], x1);
    load4f(&X2[(size_t)row * 64 + 4 * i], x2);
    load4f(&X3[(size_t)row * 64 + 4 * i], x3);
  }

  float zc[4], zp[4] = {0.f, 0.f, 0.f, 0.f};
  {
    float sx = rsum16(x0[0]*x0[0] + x0[1]*x0[1] + x0[2]*x0[2] + x0[3]*x0[3]);
    float norm = fmaxf(sqrtf(sx), MINNORM_F);
    float s = ((norm > MAXNORM_F) ? (MAXNORM_F / norm) : 1.0f) * SCALING_F;
#pragma unroll
    for (int e = 0; e < 4; ++e) zc[e] = x0[e] * s;
  }

  const float* Xi[3] = {x1, x2, x3};
#pragma unroll
  for (int li = 0; li < 3; ++li) {
    const float* xv = Xi[li];

    float p1 = xv[0]*xv[0] + xv[1]*xv[1] + xv[2]*xv[2] + xv[3]*xv[3];
    float p2 = zc[0]*zc[0]+zc[1]*zc[1]+zc[2]*zc[2]+zc[3]*zc[3];
    float p3 = zp[0]*zp[0]+zp[1]*zp[1]+zp[2]*zp[2]+zp[3]*zp[3];
    float p4 = zp[0]*zc[0]+zp[1]*zc[1]+zp[2]*zc[2]+zp[3]*zc[3];
    float p5 = zp[0]*xv[0]+zp[1]*xv[1]+zp[2]*xv[2]+zp[3]*xv[3];
    float p6 = zc[0]*xv[0]+zc[1]*xv[1]+zc[2]*xv[2]+zc[3]*xv[3];
    rsum16x6(p1, p2, p3, p4, p5, p6);
    float zc63 = __shfl(zc[3], 15, 16);   // col 63 = lane 15, elem 3
    float zp63 = __shfl(zp[3], 15, 16);

    float nzc2 = fmaxf(p2, MINNORM_F);
    float icz  = 1.0f / nzc2;
    float na2  = p2 * icz * icz;
    float r2   = na2 - 1.0f;
    float a63  = zc63 * icz;

    float sxn = fmaxf(sqrtf(p1), MINNORM_F);
    float sc  = ((sxn > MAXNORM_F) ? (MAXNORM_F / sxn) : 1.0f) * SCALING_F;
    float Sch2   = sc * sc * p1;         // Σch² (ch63 = 0: col63 zeroed in X)
    float Szp_a  = p4 * icz;
    float Sa_ch  = sc * p6 * icz;
    float Szp_ch = sc * p5;
    float Su_a   = Szp_a - na2;
    float Su2    = p3 - 2.0f * Szp_a + na2;
    float nu2    = fmaxf(Su2, MINNORM_F);
    float t1     = r2 / nu2;
    float Szp22  = fmaxf(t1*t1*Su2 + 2.0f*t1*Su_a + na2, 0.0f);
    float npn    = fmaxf(sqrtf(Szp22), MINNORM_F);
    float ipn    = 1.0f / npn;
    float zp2_63 = t1 * (zp63 - a63) + a63;
    float Szp2ch = t1 * (Szp_ch - Sa_ch) + Sa_ch;
    float rdc    = -ipn * Szp2ch;
    float rdr    = 1.0f - 2.0f*ipn*zp2_63 + ipn*ipn*Szp22;
    float m2     = 2.0f * rdc / rdr;
    float Szp2a  = t1 * Su_a + na2;
    float Srr_a  = a63 - ipn * Szp2a;
    float Sc2a   = Sa_ch - m2 * Srr_a;
    float Sc22   = Sch2 - 2.0f*m2*rdc + m2*m2*rdr;
    float Sc2ma  = Sc22 - 2.0f*Sc2a + na2;
    float nu22   = fmaxf(Sc2ma, MINNORM_F);
    float t2     = r2 / nu22;

    float zn[4];
#pragma unroll
    for (int e = 0; e < 4; ++e) {
      float ai  = zc[e] * icz;
      float zp2 = t1 * (zp[e] - ai) + ai;
      float rri = ((i == 15 && e == 3) ? 1.0f : 0.0f) - ipn * zp2;
      float c2  = sc * xv[e] - m2 * rri;
      zn[e]     = t2 * (c2 - ai) + ai;
    }
#pragma unroll
    for (int e = 0; e < 4; ++e) { zp[e] = zc[e]; zc[e] = zn[e]; }
  }

  {
    float sz = rsum16(zc[0]*zc[0] + zc[1]*zc[1] + zc[2]*zc[2] + zc[3]*zc[3]);
    float yn  = fmaxf(sqrtf(sz), MINNORM_F);
    float t   = fminf(yn, 1.0f);
    float ath = 0.5f * logf((1.0f + t) / (1.0f - t));
    float wsc = ath / yn;
    if (valid) {
      __half hv[4];
      hv[0] = __float2half(zc[0] * wsc);
      hv[1] = __float2half(zc[1] * wsc);
      hv[2] = __float2half(zc[2] * wsc);
      hv[3] = __float2half(zc[3] * wsc);
      *(uint2*)&Xh[(size_t)row * 64 + 4 * i] = *(uint2*)hv;
    }
  }
}

// ---------------------------------------------------------------------------
// CSR build (csr entries are ushort: N < 65536; plain stores — L2 coalesces)
// ---------------------------------------------------------------------------
__global__ __launch_bounds__(256) void k_deg(const int* __restrict__ dst, int E, int* deg) {
  int i0 = (blockIdx.x * 256 + threadIdx.x) * 4;
  if (i0 + 4 <= E) {
    int4 d = *(const int4*)&dst[i0];
    atomicAdd(&deg[d.x], 1);
    atomicAdd(&deg[d.y], 1);
    atomicAdd(&deg[d.z], 1);
    atomicAdd(&deg[d.w], 1);
  } else {
    for (int i = i0; i < E; ++i) atomicAdd(&deg[dst[i]], 1);
  }
}

__global__ __launch_bounds__(256) void k_scan1(const int* __restrict__ deg, int N,
                                               int* rowptr, int* bsum) {
  __shared__ int s[256];
  int t = threadIdx.x;
  int i = blockIdx.x * 256 + t;
  int v = (i < N) ? deg[i] : 0;
  s[t] = v;
  __syncthreads();
  for (int d = 1; d < 256; d <<= 1) {
    int add = (t >= d) ? s[t - d] : 0;
    __syncthreads();
    s[t] += add;
    __syncthreads();
  }
  if (i < N) rowptr[i] = s[t] - v;
  if (t == 255) bsum[blockIdx.x] = s[255];
}

__global__ __launch_bounds__(256) void k_scan2(const int* __restrict__ bsum, int NB, int* boff) {
  __shared__ int s[256];
  int t = threadIdx.x;
  int v = (t < NB) ? bsum[t] : 0;
  s[t] = v;
  __syncthreads();
  for (int d = 1; d < 256; d <<= 1) {
    int add = (t >= d) ? s[t - d] : 0;
    __syncthreads();
    s[t] += add;
    __syncthreads();
  }
  boff[t] = s[t] - v;
}

__global__ __launch_bounds__(256) void k_scan3(int* rowptr, const int* __restrict__ boff,
                                               int* cursor, int N, int E) {
  int i = blockIdx.x * 256 + threadIdx.x;
  if (i < N) {
    int v = rowptr[i] + boff[blockIdx.x];
    rowptr[i] = v;
    cursor[i] = v;
  }
  if (i == 0) rowptr[N] = E;
}

__global__ __launch_bounds__(256) void k_fill(const int* __restrict__ src,
                                              const int* __restrict__ dst, int E,
                                              int* cursor, unsigned short* __restrict__ csr) {
  int i0 = (blockIdx.x * 256 + threadIdx.x) * 4;
  if (i0 + 4 <= E) {
    int4 d = *(const int4*)&dst[i0];
    int4 s = *(const int4*)&src[i0];
    int p0 = atomicAdd(&cursor[d.x], 1);
    int p1 = atomicAdd(&cursor[d.y], 1);
    int p2 = atomicAdd(&cursor[d.z], 1);
    int p3 = atomicAdd(&cursor[d.w], 1);
    csr[p0] = (unsigned short)s.x;
    csr[p1] = (unsigned short)s.y;
    csr[p2] = (unsigned short)s.z;
    csr[p3] = (unsigned short)s.w;
  } else {
    for (int i = i0; i < E; ++i) {
      int p = atomicAdd(&cursor[dst[i]], 1);
      csr[p] = (unsigned short)src[i];
    }
  }
}

// ---------------------------------------------------------------------------
// Per-graph pooling (from Xh fp16, rows gstart[g]..gstart[g+1]) + MLP head
// ---------------------------------------------------------------------------
__global__ __launch_bounds__(128) void k_mlp(const __half* __restrict__ Xh,
                                             const int* __restrict__ gstart,
                                             const float* __restrict__ fc1W, const float* __restrict__ fc1b,
                                             const float* __restrict__ fc2W, const float* __restrict__ fc2b,
                                             const float* __restrict__ fc3W, const float* __restrict__ fc3b,
                                             float* __restrict__ out) {
  __shared__ float p2s[2][64];
  __shared__ float p[64], o1[128], o2[64], lg[10], red[2];
  int g = blockIdx.x, t = threadIdx.x;
  int beg = gstart[g], end = gstart[g + 1];
  {
    int half = t >> 6, c = t & 63;
    float a = 0.f;
    int r = beg + half;
    for (; r + 6 <= end; r += 8) {         // 4 independent loads per iter
      float v0 = __half2float(Xh[(size_t)(r + 0) * 64 + c]);
      float v1 = __half2float(Xh[(size_t)(r + 2) * 64 + c]);
      float v2 = __half2float(Xh[(size_t)(r + 4) * 64 + c]);
      float v3 = __half2float(Xh[(size_t)(r + 6) * 64 + c]);
      a += (v0 + v1) + (v2 + v3);
    }
    for (; r < end; r += 2) a += __half2float(Xh[(size_t)r * 64 + c]);
    p2s[half][c] = a;
  }
  __syncthreads();
  if (t < 64) p[t] = p2s[0][t] + p2s[1][t];
  __syncthreads();
  {
    float a = fc1b[t];
    for (int k = 0; k < 64; ++k) a = fmaf(p[k], fc1W[k * 128 + t], a);
    o1[t] = fmaxf(a, 0.f);
  }
  __syncthreads();
  if (t < 64) {
    float a = fc2b[t];
    for (int k = 0; k < 128; ++k) a = fmaf(o1[k], fc2W[k * 64 + t], a);
    o2[t] = fmaxf(a, 0.f);
  }
  __syncthreads();
  if (t < 10) {
    float a = fc3b[t];
    for (int k = 0; k < 64; ++k) a = fmaf(o2[k], fc3W[k * 10 + t], a);
    lg[t] = a;
  }
  __syncthreads();
  if (t == 0) {
    float mx = lg[0];
    for (int j = 1; j < 10; ++j) mx = fmaxf(mx, lg[j]);
    float s = 0.f;
    for (int j = 0; j < 10; ++j) s += expf(lg[j] - mx);
    red[0] = mx;
    red[1] = logf(s);
  }
  __syncthreads();
  if (t < 10) out[(size_t)g * 10 + t] = lg[t] - red[0] - red[1];
}

// ---------------------------------------------------------------------------
extern "C" void kernel_launch(void* const* d_in, const int* in_sizes, int n_in,
                              void* d_out, int out_size, void* d_ws, size_t ws_size,
                              hipStream_t stream) {
  const float* x_in  = (const float*)d_in[0];
  const int*   ei    = (const int*)d_in[1];
  const int*   batch = (const int*)d_in[2];
  const float* W0    = (const float*)d_in[3];
  const float* b0    = (const float*)d_in[4];
  const float* cW1   = (const float*)d_in[5];
  const float* cb1   = (const float*)d_in[6];
  const float* gamma = (const float*)d_in[7];
  const float* beta  = (const float*)d_in[8];
  const float* cW2   = (const float*)d_in[9];
  const float* cb2   = (const float*)d_in[10];
  const float* fc1W  = (const float*)d_in[11];
  const float* fc1b  = (const float*)d_in[12];
  const float* fc2W  = (const float*)d_in[13];
  const float* fc2b  = (const float*)d_in[14];
  const float* fc3W  = (const float*)d_in[15];
  const float* fc3b  = (const float*)d_in[16];
  float* out = (float*)d_out;

  const int N = in_sizes[0] / 128;
  const int E = in_sizes[1] / 2;
  const int L = in_sizes[5] / (64 * 64);
  const int G = out_size / 10;
  const int* src = ei;
  const int* dst = ei + E;

  char* ws = (char*)d_ws;
  size_t off = 0;
  auto alloc = [&](size_t bytes) -> char* {
    char* p = ws + off;
    off += (bytes + 255) & ~(size_t)255;
    return p;
  };
  __half* X0  = (__half*)alloc((size_t)N * 64 * 2);
  __half* X1  = (__half*)alloc((size_t)N * 64 * 2);
  __half* X2  = (__half*)alloc((size_t)N * 64 * 2);
  __half* X3  = (__half*)alloc((size_t)N * 64 * 2);
  __half* Bf  = (__half*)alloc((size_t)N * 64 * 2);
  __half* Xh  = (__half*)alloc((size_t)N * 64 * 2);
  __half* W0T = (__half*)alloc((size_t)64 * 128 * 2);
  __half* W1T = (__half*)alloc((size_t)L * 64 * 64 * 2);
  __half* W2T = (__half*)alloc((size_t)L * 64 * 64 * 2);
  int*    gstart = (int*)alloc((size_t)(G + 1) * 4);
  // ---- zeroed region: deg, gstatAll (contiguous) ----
  int*   deg  = (int*)alloc((size_t)N * 4);
  float* gstatAll = (float*)alloc((size_t)3 * 128 * 4);
  char*  zero_end = ws + off;
  // ---------------------------------------------------
  int*   rowptr = (int*)alloc((size_t)(N + 1) * 4);
  int*   cursor = (int*)alloc((size_t)N * 4);
  unsigned short* csr = (unsigned short*)alloc((size_t)E * 2);
  int*   bsum   = (int*)alloc(256 * 4);
  int*   boff   = (int*)alloc(256 * 4);
  __half* Xs[4] = {X0, X1, X2, X3};

  hipMemsetAsync(deg, 0, (size_t)(zero_end - (char*)deg), stream);

  const int mmGrid    = (N + 63) / 64;
  const int zcGrid    = (N + 15) / 16;
  const int edge4Grid = (E / 4 + 255) / 256 + 1;
  const int wcvtGrid  = (((L * 4096 > 8192) ? L * 4096 : 8192) + 255) / 256;

  k_wcvt<<<wcvtGrid, 256, 0, stream>>>(W0, cW1, cW2, L, W0T, W1T, W2T);
  k_gb<<<(N + 255) / 256, 256, 0, stream>>>(batch, N, G, gstart);

  k_mm0<<<mmGrid, 256, 0, stream>>>(x_in, W0T, b0, X0, N);

  k_deg<<<edge4Grid, 256, 0, stream>>>(dst, E, deg);
  const int NB = (N + 255) / 256;
  k_scan1<<<NB, 256, 0, stream>>>(deg, N, rowptr, bsum);
  k_scan2<<<1, 256, 0, stream>>>(bsum, NB, boff);
  k_scan3<<<NB, 256, 0, stream>>>(rowptr, boff, cursor, N, E);
  k_fill<<<edge4Grid, 256, 0, stream>>>(src, dst, E, cursor, csr);

  for (int i = 0; i < L; ++i) {
    float* gstat = gstatAll + (size_t)i * 128;
    k_layer1<<<mmGrid, 256, 0, stream>>>(Xs[i], rowptr, csr,
                                         W1T + (size_t)i * 4096, cb1 + i * 64,
                                         Bf, gstat, N);
    k_layer2<<<mmGrid, 256, 0, stream>>>(Bf, W2T + (size_t)i * 4096, cb2 + i * 64,
                                         gstat, gamma + i * 64, beta + i * 64,
                                         Xs[i + 1], N);
  }

  k_zchain<<<zcGrid, 256, 0, stream>>>(X0, X1, X2, X3, Xh, N);

  k_mlp<<<G, 128, 0, stream>>>(Xh, gstart, fc1W, fc1b, fc2W, fc2b, fc3W, fc3b, out);
}